// Round 11
// baseline (213.016 us; speedup 1.0000x reference)
//
#include <hip/hip_runtime.h>
#include <hip/hip_bf16.h>
#include <math.h>

#define N_Q 16384
#define N_M 16384
#define DIM 128
#define KNN 5
#define SPLITS 8
#define COLS_PER_SPLIT (N_M / SPLITS)   // 2048
#define ITERS (COLS_PER_SPLIT / 128)    // 16
#define BROWS 128                        // rows per block (4 waves x 32)
#define TSEL 8                           // keys kept per (row, split)
#define TSEL2 16                         // candidates re-ranked per query
#define LLIST 4                          // per-lane sorted list depth
#define BIGF 3.0e38f

typedef __bf16 bf16x8 __attribute__((ext_vector_type(8)));
typedef float f32x4 __attribute__((ext_vector_type(4)));

__device__ __forceinline__ void gl2lds16(const void* g, void* l) {
    __builtin_amdgcn_global_load_lds(
        (const __attribute__((address_space(1))) void*)g,
        (__attribute__((address_space(3))) void*)l, 16, 0, 0);
}

// med3: with a<=b (sorted list invariant), med3(a,b,k) == max(a, min(b,k)).
__device__ __forceinline__ unsigned umed3(unsigned a, unsigned b, unsigned c) {
    unsigned d;
    asm("v_med3_u32 %0, %1, %2, %3" : "=v"(d) : "v"(a), "v"(b), "v"(c));
    return d;
}

// branchless sorted insert (ascending), depth D: (D-1) med3 + 1 min.
template <int D>
__device__ __forceinline__ void insD(unsigned (&L)[D], unsigned k) {
#pragma unroll
    for (int i = D - 1; i >= 1; --i) L[i] = umed3(L[i - 1], L[i], k);
    L[0] = min(L[0], k);
}

// ---------------------------------------------------------------------------
// Kernel A: per-row sumsq + bf16 conversion + biased m2.
// mb is stored PRE-SCALED by -2 (exact in bf16): MFMA with C=m2b directly
// produces key score s = m2+256-2dot > 0 (uint order == score order).
// ---------------------------------------------------------------------------
__global__ void prep_kernel(const float* __restrict__ q,
                            const float* __restrict__ mem,
                            float* __restrict__ q2, float* __restrict__ m2,
                            float* __restrict__ m2b,
                            __hip_bfloat16* __restrict__ qb,
                            __hip_bfloat16* __restrict__ mb) {
    int gt = blockIdx.x * blockDim.x + threadIdx.x;
    int wid = gt >> 6;
    int lane = gt & 63;
    bool isq = wid < N_Q;
    int r = isq ? wid : wid - N_Q;
    const float* src = (isq ? q : mem) + (size_t)r * DIM;
    __hip_bfloat16* bdst = (isq ? qb : mb) + (size_t)r * DIM;
    float2 v = reinterpret_cast<const float2*>(src)[lane];
    float sc = isq ? 1.0f : -2.0f;   // B operand carries the -2 factor
    __hip_bfloat162 bv;
    bv.x = __float2bfloat16(sc * v.x);
    bv.y = __float2bfloat16(sc * v.y);
    reinterpret_cast<__hip_bfloat162*>(bdst)[lane] = bv;
    float s = fmaf(v.x, v.x, v.y * v.y);
#pragma unroll
    for (int off = 32; off > 0; off >>= 1) s += __shfl_down(s, off, 64);
    if (lane == 0) {
        if (isq) {
            q2[r] = s;
        } else {
            m2[r] = s;
            m2b[r] = s + 256.0f;  // key = m2b-2dot >= ~216 > 0 always
        }
    }
}

// ---------------------------------------------------------------------------
// Kernel B: bf16 MFMA scoring + branchless med3 top-4 selection.
// Single 32 KB LDS buffer (r10 dbuf was neutral and halved occupancy
// headroom); NO min-waves launch bound — with 33 KB LDS and ~96 VGPR the
// HW can host 4 blocks/CU, making the 1024-block grid fully resident.
// acc C-initialized to m2b (column-constant), mb pre-scaled by -2: score
// materializes in acc; per key = and_or(pack) + 4-op insert.
// ---------------------------------------------------------------------------
__global__ __launch_bounds__(256) void knn_tops_kernel(
    const __hip_bfloat16* __restrict__ qb, const __hip_bfloat16* __restrict__ mb,
    const float* __restrict__ m2b, unsigned* __restrict__ candK) {
    __shared__ __align__(16) unsigned char smem[32768];
    const int tid = threadIdx.x;
    const int w = tid >> 6;
    const int lane = tid & 63;
    const int i16 = lane & 15;
    const int g = lane >> 4;
    const int row0 = blockIdx.x * BROWS;
    const int col0 = blockIdx.y * COLS_PER_SPLIT;

    // ---- A fragments: 2 row-tiles x 4 k-steps (loop-invariant) ----
    bf16x8 afrag[2][4];
#pragma unroll
    for (int ti = 0; ti < 2; ++ti) {
        const __hip_bfloat16* qrow =
            qb + (size_t)(row0 + w * 32 + ti * 16 + i16) * DIM;
#pragma unroll
        for (int ks = 0; ks < 4; ++ks)
            afrag[ti][ks] = *reinterpret_cast<const bf16x8*>(qrow + ks * 32 + g * 8);
    }

    // ---- sorted lists (packed keys), 8 rows x 4, ascending ----
    unsigned lst[8][LLIST];
#pragma unroll
    for (int rr = 0; rr < 8; ++rr)
#pragma unroll
        for (int j = 0; j < LLIST; ++j) lst[rr][j] = 0xFFFFFFFFu;

    // ---- loop-invariant addressing ----
    const int lds_base = i16 * 256 + ((g ^ (i16 & 7)) << 4);
    int soff[8];
#pragma unroll
    for (int it = 0; it < 8; ++it) {
        int fg = w * 512 + it * 64 + lane;
        int c = fg >> 4, sg = fg & 15;
        int gk = (sg & 8) | ((sg ^ c) & 7);
        soff[it] = c * DIM + gk * 8;
    }
    const __hip_bfloat16* mbt = mb + (size_t)col0 * DIM;

    for (int t = 0; t < ITERS; ++t) {
        __syncthreads();  // all waves done reading previous tile
#pragma unroll
        for (int it = 0; it < 8; ++it)
            gl2lds16(mbt + soff[it], smem + w * 8192 + it * 1024);
        mbt += 128 * DIM;
        __syncthreads();

        // per-tile m2b + col constants (8 broadcast-ish loads, L1/L2-hot)
        float m2r[8];
        unsigned colv[8];
#pragma unroll
        for (int h = 0; h < 2; ++h)
#pragma unroll
            for (int c = 0; c < 4; ++c) {
                int cl = col0 + t * 128 + h * 64 + c * 16 + i16;
                m2r[h * 4 + c] = m2b[cl];
                colv[h * 4 + c] = (unsigned)cl;
            }
#pragma unroll
        for (int half = 0; half < 2; ++half) {
#pragma unroll
            for (int cc = 0; cc < 2; ++cc) {  // ct chunk of 2
                f32x4 acc[2][2];
#pragma unroll
                for (int ti = 0; ti < 2; ++ti)
#pragma unroll
                    for (int c2 = 0; c2 < 2; ++c2) {
                        float m = m2r[half * 4 + cc * 2 + c2];
                        acc[ti][c2] = (f32x4){m, m, m, m};
                    }
#pragma unroll
                for (int ks = 0; ks < 4; ++ks) {
                    const unsigned char* bp =
                        smem + (lds_base ^ (ks << 6)) + half * 16384;
#pragma unroll
                    for (int c2 = 0; c2 < 2; ++c2) {
                        int ct = cc * 2 + c2;
                        bf16x8 bfr =
                            *reinterpret_cast<const bf16x8*>(bp + ct * 4096);
                        acc[0][c2] = __builtin_amdgcn_mfma_f32_16x16x32_bf16(
                            afrag[0][ks], bfr, acc[0][c2], 0, 0, 0);
                        acc[1][c2] = __builtin_amdgcn_mfma_f32_16x16x32_bf16(
                            afrag[1][ks], bfr, acc[1][c2], 0, 0, 0);
                    }
                }
#pragma unroll
                for (int ti = 0; ti < 2; ++ti) {
#pragma unroll
                    for (int r = 0; r < 4; ++r) {
                        const int rr = ti * 4 + r;
#pragma unroll
                        for (int c2 = 0; c2 < 2; ++c2) {
                            unsigned k = (__float_as_uint(acc[ti][c2][r]) &
                                          0xFFFFC000u) |
                                         colv[half * 4 + cc * 2 + c2];
                            insD(lst[rr], k);
                        }
                    }
                }
            }
        }
    }

    __syncthreads();  // tile LDS dead; overlay merge buffer

    // ---- phase 1: SNAPSHOT partner's 4 keys, then insert ----
#pragma unroll
    for (int rr = 0; rr < 8; ++rr) {
        unsigned pv[LLIST];
#pragma unroll
        for (int j = 0; j < LLIST; ++j)
            pv[j] = (unsigned)__shfl_xor((int)lst[rr][j], 8, 64);
#pragma unroll
        for (int j = 0; j < LLIST; ++j) insD(lst[rr], pv[j]);
    }
    // ---- dump: 8 lanes x 4 keys per row, stride 33 ----
    unsigned* MG = (unsigned*)smem;  // [128][33] = 16.9 KB
    if (i16 < 8) {
#pragma unroll
        for (int rr = 0; rr < 8; ++rr) {
            int row = w * 32 + (rr >> 2) * 16 + g * 4 + (rr & 3);
#pragma unroll
            for (int j = 0; j < LLIST; ++j)
                MG[row * 33 + i16 * LLIST + j] = lst[rr][j];
        }
    }
    __syncthreads();
    // ---- phase 2: thread per row, med3 depth-8 over 32 keys ----
    if (tid < BROWS) {
        unsigned bk[TSEL];
#pragma unroll
        for (int j = 0; j < TSEL; ++j) bk[j] = 0xFFFFFFFFu;
        for (int c = 0; c < 32; ++c) {
            unsigned k = MG[tid * 33 + c];
            insD(bk, k);
        }
        size_t base = (size_t)(row0 + tid) * (SPLITS * TSEL) + blockIdx.y * TSEL;
        *reinterpret_cast<uint4*>(candK + base) =
            make_uint4(bk[0], bk[1], bk[2], bk[3]);
        *reinterpret_cast<uint4*>(candK + base + 4) =
            make_uint4(bk[4], bk[5], bk[6], bk[7]);
    }
}

// ---------------------------------------------------------------------------
// Kernel C: global merge (replay-proven). Thread per row: 64 packed keys ->
// top-16 -> candidate indices.
// ---------------------------------------------------------------------------
__global__ void merge_kernel(const unsigned* __restrict__ candK,
                             int* __restrict__ candI2) {
    int row = blockIdx.x * blockDim.x + threadIdx.x;
    const unsigned* ck = candK + (size_t)row * (SPLITS * TSEL);
    unsigned v[TSEL2];
#pragma unroll
    for (int j = 0; j < TSEL2; ++j) v[j] = 0xFFFFFFFFu;
    for (int s4 = 0; s4 < 16; ++s4) {
        uint4 kk = reinterpret_cast<const uint4*>(ck)[s4];
        insD(v, kk.x);
        insD(v, kk.y);
        insD(v, kk.z);
        insD(v, kk.w);
    }
#pragma unroll
    for (int j = 0; j < TSEL2; ++j)
        candI2[(size_t)row * TSEL2 + j] = (int)(v[j] & 0x3FFFu);
}

// ---------------------------------------------------------------------------
// Kernel D: exact fp32 re-rank of 16 candidates/query + adaptive-KNN output.
// (Replay-proven.) Wave per query; quad-cooperative dots; 5 shuffle-argmin
// extractions -> exact top-5.
// ---------------------------------------------------------------------------
__global__ __launch_bounds__(256) void finalize_kernel(
    const float* __restrict__ q, const float* __restrict__ mem,
    const float* __restrict__ q2, const float* __restrict__ m2,
    const int* __restrict__ candI2, const float* __restrict__ scaleb,
    float* __restrict__ out) {
    int wv = threadIdx.x >> 6, lane = threadIdx.x & 63;
    int n = blockIdx.x * 4 + wv;
    int cand = lane >> 2, qd = lane & 3;
    int ci = candI2[(size_t)n * TSEL2 + cand];
    const float4* qr = reinterpret_cast<const float4*>(q + (size_t)n * DIM) + qd * 8;
    const float4* mr = reinterpret_cast<const float4*>(mem + (size_t)ci * DIM) + qd * 8;
    float dot = 0.f;
#pragma unroll
    for (int k = 0; k < 8; ++k) {
        float4 a = qr[k], b = mr[k];
        dot = fmaf(a.x, b.x, fmaf(a.y, b.y, fmaf(a.z, b.z, fmaf(a.w, b.w, dot))));
    }
    dot += __shfl_xor(dot, 1, 64);
    dot += __shfl_xor(dot, 2, 64);
    float v = (qd == 0) ? (q2[n] + m2[ci] - 2.f * dot) : BIGF;

    float dk[KNN]; int ik[KNN];
#pragma unroll
    for (int r = 0; r < KNN; ++r) {
        float mv = v; int ml = lane;
#pragma unroll
        for (int off = 32; off > 0; off >>= 1) {
            float ov = __shfl_xor(mv, off, 64);
            int   ol = __shfl_xor(ml, off, 64);
            if (ov < mv || (ov == mv && ol < ml)) { mv = ov; ml = ol; }
        }
        dk[r] = sqrtf(fmaxf(mv, 1e-12f));
        ik[r] = __shfl(ci, ml, 64);
        if (lane == ml) v = BIGF;
    }
    if (lane == 0) {
        float dmin = dk[0];
        float se = 0.f, wd = 0.f, sm = 0.f, ssc = 0.f;
#pragma unroll
        for (int j = 0; j < KNN; ++j) {
            float e = expf(-(dk[j] - dmin));
            se += e;
            wd = fmaf(e, dk[j], wd);
            sm += dk[j];
            ssc += scaleb[ik[j]];
        }
        wd /= se;
        float scale = ssc * 0.2f;
        float nd = wd / fmaxf(scale, 1e-6f);
        float mean = sm * 0.2f;
        float var = 0.f;
#pragma unroll
        for (int j = 0; j < KNN; ++j) {
            float dd = dk[j] - mean;
            var = fmaf(dd, dd, var);
        }
        var *= 0.2f;
        float cons = sqrtf(var) / fmaxf(mean, 1e-6f);
        out[n] = nd * (1.f + 0.5f * cons);
    }
}

// ---------------------------------------------------------------------------
// ws: q2[N] | m2[M] | m2b[M] | qb bf16 | mb bf16(-2x) | candK[N*64] |
// candI2[N*16]  (~14 MB)
// ---------------------------------------------------------------------------
extern "C" void kernel_launch(void* const* d_in, const int* in_sizes, int n_in,
                              void* d_out, int out_size, void* d_ws,
                              size_t ws_size, hipStream_t stream) {
    const float* query  = (const float*)d_in[0];
    const float* mem    = (const float*)d_in[1];
    const float* scaleb = (const float*)d_in[2];
    float* out = (float*)d_out;

    float* q2 = (float*)d_ws;
    float* m2 = q2 + N_Q;
    float* m2b = m2 + N_M;
    __hip_bfloat16* qb = (__hip_bfloat16*)(m2b + N_M);
    __hip_bfloat16* mb = qb + (size_t)N_Q * DIM;
    unsigned* candK = (unsigned*)(mb + (size_t)N_M * DIM);
    int* candI2 = (int*)(candK + (size_t)N_Q * SPLITS * TSEL);

    prep_kernel<<<(N_Q + N_M) / 4, 256, 0, stream>>>(query, mem, q2, m2, m2b,
                                                     qb, mb);
    dim3 gridB(N_Q / BROWS, SPLITS);
    knn_tops_kernel<<<gridB, 256, 0, stream>>>(qb, mb, m2b, candK);
    merge_kernel<<<N_Q / 256, 256, 0, stream>>>(candK, candI2);
    finalize_kernel<<<N_Q / 4, 256, 0, stream>>>(query, mem, q2, m2, candI2,
                                                 scaleb, out);
}

// Round 12
// 200.458 us; speedup vs baseline: 1.0626x; 1.0626x over previous
//
#include <hip/hip_runtime.h>
#include <hip/hip_bf16.h>
#include <math.h>

#define N_Q 16384
#define N_M 16384
#define DIM 128
#define KNN 5
#define SPLITS 8
#define COLS_PER_SPLIT (N_M / SPLITS)   // 2048
#define ITERS (COLS_PER_SPLIT / 128)    // 16
#define BROWS 256                        // rows per block (4 waves x 64)
#define TSEL 8                           // keys kept per (row, split)
#define TSEL2 16                         // candidates re-ranked per query
#define LLIST 4                          // per-lane sorted list depth
#define BIGF 3.0e38f

typedef __bf16 bf16x8 __attribute__((ext_vector_type(8)));
typedef float f32x4 __attribute__((ext_vector_type(4)));

__device__ __forceinline__ void gl2lds16(const void* g, void* l) {
    __builtin_amdgcn_global_load_lds(
        (const __attribute__((address_space(1))) void*)g,
        (__attribute__((address_space(3))) void*)l, 16, 0, 0);
}

// med3: with a<=b (sorted list invariant), med3(a,b,k) == max(a, min(b,k)).
__device__ __forceinline__ unsigned umed3(unsigned a, unsigned b, unsigned c) {
    unsigned d;
    asm("v_med3_u32 %0, %1, %2, %3" : "=v"(d) : "v"(a), "v"(b), "v"(c));
    return d;
}

// branchless sorted insert (ascending), depth D: (D-1) med3 + 1 min.
template <int D>
__device__ __forceinline__ void insD(unsigned (&L)[D], unsigned k) {
#pragma unroll
    for (int i = D - 1; i >= 1; --i) L[i] = umed3(L[i - 1], L[i], k);
    L[0] = min(L[0], k);
}

// ---------------------------------------------------------------------------
// Kernel A: per-row sumsq + bf16 conversion + biased m2.
// mb is stored PRE-SCALED by -2 (exact in bf16): MFMA with C=m2b directly
// produces key score s = m2+256-2dot > 0 (uint order == score order).
// ---------------------------------------------------------------------------
__global__ void prep_kernel(const float* __restrict__ q,
                            const float* __restrict__ mem,
                            float* __restrict__ q2, float* __restrict__ m2,
                            float* __restrict__ m2b,
                            __hip_bfloat16* __restrict__ qb,
                            __hip_bfloat16* __restrict__ mb) {
    int gt = blockIdx.x * blockDim.x + threadIdx.x;
    int wid = gt >> 6;
    int lane = gt & 63;
    bool isq = wid < N_Q;
    int r = isq ? wid : wid - N_Q;
    const float* src = (isq ? q : mem) + (size_t)r * DIM;
    __hip_bfloat16* bdst = (isq ? qb : mb) + (size_t)r * DIM;
    float2 v = reinterpret_cast<const float2*>(src)[lane];
    float sc = isq ? 1.0f : -2.0f;   // B operand carries the -2 factor
    __hip_bfloat162 bv;
    bv.x = __float2bfloat16(sc * v.x);
    bv.y = __float2bfloat16(sc * v.y);
    reinterpret_cast<__hip_bfloat162*>(bdst)[lane] = bv;
    float s = fmaf(v.x, v.x, v.y * v.y);
#pragma unroll
    for (int off = 32; off > 0; off >>= 1) s += __shfl_down(s, off, 64);
    if (lane == 0) {
        if (isq) {
            q2[r] = s;
        } else {
            m2[r] = s;
            m2b[r] = s + 256.0f;  // key = m2b-2dot >= ~216 > 0 always
        }
    }
}

// ---------------------------------------------------------------------------
// Kernel B: bf16 MFMA scoring + branchless med3 top-4 selection.
// BROWS=256: each wave owns FOUR 16-row MFMA tiles -> every ds_read_b128
// B-fragment feeds 4 MFMAs (halves LDS-pipe time vs 2 row-tiles) and all
// per-wave-tile overhead (staging, m2b loads, addressing) amortizes over
// 2x keys. Lists: 16 rows x depth-4 = 64 VGPRs; afrag 64; acc 32/chunk ->
// demand ~200-220, so (256,2): 256-VGPR cap, grid 512 = exactly 2
// blocks/CU (tail-free). Per-lane per-split column coverage identical to
// the proven rounds -> same retention margins.
// ---------------------------------------------------------------------------
__global__ __launch_bounds__(256, 2) void knn_tops_kernel(
    const __hip_bfloat16* __restrict__ qb, const __hip_bfloat16* __restrict__ mb,
    const float* __restrict__ m2b, unsigned* __restrict__ candK) {
    __shared__ __align__(16) unsigned char smem[33792];  // 32KB tile / merge ovl
    const int tid = threadIdx.x;
    const int w = tid >> 6;
    const int lane = tid & 63;
    const int i16 = lane & 15;
    const int g = lane >> 4;
    const int row0 = blockIdx.x * BROWS;
    const int col0 = blockIdx.y * COLS_PER_SPLIT;

    // ---- A fragments: 4 row-tiles x 4 k-steps (loop-invariant) ----
    bf16x8 afrag[4][4];
#pragma unroll
    for (int ti = 0; ti < 4; ++ti) {
        const __hip_bfloat16* qrow =
            qb + (size_t)(row0 + w * 64 + ti * 16 + i16) * DIM;
#pragma unroll
        for (int ks = 0; ks < 4; ++ks)
            afrag[ti][ks] = *reinterpret_cast<const bf16x8*>(qrow + ks * 32 + g * 8);
    }

    // ---- sorted lists (packed keys), 16 rows x 4, ascending ----
    unsigned lst[16][LLIST];
#pragma unroll
    for (int rr = 0; rr < 16; ++rr)
#pragma unroll
        for (int j = 0; j < LLIST; ++j) lst[rr][j] = 0xFFFFFFFFu;

    // ---- loop-invariant addressing ----
    const int lds_base = i16 * 256 + ((g ^ (i16 & 7)) << 4);
    int soff[8];
#pragma unroll
    for (int it = 0; it < 8; ++it) {
        int fg = w * 512 + it * 64 + lane;
        int c = fg >> 4, sg = fg & 15;
        int gk = (sg & 8) | ((sg ^ c) & 7);
        soff[it] = c * DIM + gk * 8;
    }
    const __hip_bfloat16* mbt = mb + (size_t)col0 * DIM;

    for (int t = 0; t < ITERS; ++t) {
        __syncthreads();  // all waves done reading previous tile
#pragma unroll
        for (int it = 0; it < 8; ++it)
            gl2lds16(mbt + soff[it], smem + w * 8192 + it * 1024);
        mbt += 128 * DIM;
        __syncthreads();

        // per-tile m2b + col constants
        float m2r[8];
        unsigned colv[8];
#pragma unroll
        for (int h = 0; h < 2; ++h)
#pragma unroll
            for (int c = 0; c < 4; ++c) {
                int cl = col0 + t * 128 + h * 64 + c * 16 + i16;
                m2r[h * 4 + c] = m2b[cl];
                colv[h * 4 + c] = (unsigned)cl;
            }
#pragma unroll
        for (int half = 0; half < 2; ++half) {
#pragma unroll
            for (int cc = 0; cc < 2; ++cc) {  // ct chunk of 2
                f32x4 acc[4][2];
#pragma unroll
                for (int ti = 0; ti < 4; ++ti)
#pragma unroll
                    for (int c2 = 0; c2 < 2; ++c2) {
                        float m = m2r[half * 4 + cc * 2 + c2];
                        acc[ti][c2] = (f32x4){m, m, m, m};
                    }
#pragma unroll
                for (int ks = 0; ks < 4; ++ks) {
                    const unsigned char* bp =
                        smem + (lds_base ^ (ks << 6)) + half * 16384;
#pragma unroll
                    for (int c2 = 0; c2 < 2; ++c2) {
                        int ct = cc * 2 + c2;
                        bf16x8 bfr =
                            *reinterpret_cast<const bf16x8*>(bp + ct * 4096);
#pragma unroll
                        for (int ti = 0; ti < 4; ++ti)
                            acc[ti][c2] = __builtin_amdgcn_mfma_f32_16x16x32_bf16(
                                afrag[ti][ks], bfr, acc[ti][c2], 0, 0, 0);
                    }
                }
#pragma unroll
                for (int ti = 0; ti < 4; ++ti) {
#pragma unroll
                    for (int r = 0; r < 4; ++r) {
                        const int rr = ti * 4 + r;
#pragma unroll
                        for (int c2 = 0; c2 < 2; ++c2) {
                            unsigned k = (__float_as_uint(acc[ti][c2][r]) &
                                          0xFFFFC000u) |
                                         colv[half * 4 + cc * 2 + c2];
                            insD(lst[rr], k);
                        }
                    }
                }
            }
        }
    }

    __syncthreads();  // tile LDS dead; overlay merge buffer

    // ---- phase 1: SNAPSHOT partner's 4 keys, then insert ----
#pragma unroll
    for (int rr = 0; rr < 16; ++rr) {
        unsigned pv[LLIST];
#pragma unroll
        for (int j = 0; j < LLIST; ++j)
            pv[j] = (unsigned)__shfl_xor((int)lst[rr][j], 8, 64);
#pragma unroll
        for (int j = 0; j < LLIST; ++j) insD(lst[rr], pv[j]);
    }
    // ---- dump: 8 lanes x 4 keys per row, stride 33 ([256][33] = 33.8 KB) ----
    unsigned* MG = (unsigned*)smem;
    if (i16 < 8) {
#pragma unroll
        for (int rr = 0; rr < 16; ++rr) {
            int row = w * 64 + (rr >> 2) * 16 + g * 4 + (rr & 3);
#pragma unroll
            for (int j = 0; j < LLIST; ++j)
                MG[row * 33 + i16 * LLIST + j] = lst[rr][j];
        }
    }
    __syncthreads();
    // ---- phase 2: all 256 threads, one per row; med3 depth-8 over 32 keys ----
    {
        unsigned bk[TSEL];
#pragma unroll
        for (int j = 0; j < TSEL; ++j) bk[j] = 0xFFFFFFFFu;
        for (int c = 0; c < 32; ++c) {
            unsigned k = MG[tid * 33 + c];
            insD(bk, k);
        }
        size_t base = (size_t)(row0 + tid) * (SPLITS * TSEL) + blockIdx.y * TSEL;
        *reinterpret_cast<uint4*>(candK + base) =
            make_uint4(bk[0], bk[1], bk[2], bk[3]);
        *reinterpret_cast<uint4*>(candK + base + 4) =
            make_uint4(bk[4], bk[5], bk[6], bk[7]);
    }
}

// ---------------------------------------------------------------------------
// Kernel C: global merge (replay-proven). Thread per row: 64 packed keys ->
// top-16 -> candidate indices.
// ---------------------------------------------------------------------------
__global__ void merge_kernel(const unsigned* __restrict__ candK,
                             int* __restrict__ candI2) {
    int row = blockIdx.x * blockDim.x + threadIdx.x;
    const unsigned* ck = candK + (size_t)row * (SPLITS * TSEL);
    unsigned v[TSEL2];
#pragma unroll
    for (int j = 0; j < TSEL2; ++j) v[j] = 0xFFFFFFFFu;
    for (int s4 = 0; s4 < 16; ++s4) {
        uint4 kk = reinterpret_cast<const uint4*>(ck)[s4];
        insD(v, kk.x);
        insD(v, kk.y);
        insD(v, kk.z);
        insD(v, kk.w);
    }
#pragma unroll
    for (int j = 0; j < TSEL2; ++j)
        candI2[(size_t)row * TSEL2 + j] = (int)(v[j] & 0x3FFFu);
}

// ---------------------------------------------------------------------------
// Kernel D: exact fp32 re-rank of 16 candidates/query + adaptive-KNN output.
// (Replay-proven.) Wave per query; quad-cooperative dots; 5 shuffle-argmin
// extractions -> exact top-5.
// ---------------------------------------------------------------------------
__global__ __launch_bounds__(256) void finalize_kernel(
    const float* __restrict__ q, const float* __restrict__ mem,
    const float* __restrict__ q2, const float* __restrict__ m2,
    const int* __restrict__ candI2, const float* __restrict__ scaleb,
    float* __restrict__ out) {
    int wv = threadIdx.x >> 6, lane = threadIdx.x & 63;
    int n = blockIdx.x * 4 + wv;
    int cand = lane >> 2, qd = lane & 3;
    int ci = candI2[(size_t)n * TSEL2 + cand];
    const float4* qr = reinterpret_cast<const float4*>(q + (size_t)n * DIM) + qd * 8;
    const float4* mr = reinterpret_cast<const float4*>(mem + (size_t)ci * DIM) + qd * 8;
    float dot = 0.f;
#pragma unroll
    for (int k = 0; k < 8; ++k) {
        float4 a = qr[k], b = mr[k];
        dot = fmaf(a.x, b.x, fmaf(a.y, b.y, fmaf(a.z, b.z, fmaf(a.w, b.w, dot))));
    }
    dot += __shfl_xor(dot, 1, 64);
    dot += __shfl_xor(dot, 2, 64);
    float v = (qd == 0) ? (q2[n] + m2[ci] - 2.f * dot) : BIGF;

    float dk[KNN]; int ik[KNN];
#pragma unroll
    for (int r = 0; r < KNN; ++r) {
        float mv = v; int ml = lane;
#pragma unroll
        for (int off = 32; off > 0; off >>= 1) {
            float ov = __shfl_xor(mv, off, 64);
            int   ol = __shfl_xor(ml, off, 64);
            if (ov < mv || (ov == mv && ol < ml)) { mv = ov; ml = ol; }
        }
        dk[r] = sqrtf(fmaxf(mv, 1e-12f));
        ik[r] = __shfl(ci, ml, 64);
        if (lane == ml) v = BIGF;
    }
    if (lane == 0) {
        float dmin = dk[0];
        float se = 0.f, wd = 0.f, sm = 0.f, ssc = 0.f;
#pragma unroll
        for (int j = 0; j < KNN; ++j) {
            float e = expf(-(dk[j] - dmin));
            se += e;
            wd = fmaf(e, dk[j], wd);
            sm += dk[j];
            ssc += scaleb[ik[j]];
        }
        wd /= se;
        float scale = ssc * 0.2f;
        float nd = wd / fmaxf(scale, 1e-6f);
        float mean = sm * 0.2f;
        float var = 0.f;
#pragma unroll
        for (int j = 0; j < KNN; ++j) {
            float dd = dk[j] - mean;
            var = fmaf(dd, dd, var);
        }
        var *= 0.2f;
        float cons = sqrtf(var) / fmaxf(mean, 1e-6f);
        out[n] = nd * (1.f + 0.5f * cons);
    }
}

// ---------------------------------------------------------------------------
// ws: q2[N] | m2[M] | m2b[M] | qb bf16 | mb bf16(-2x) | candK[N*64] |
// candI2[N*16]  (~14 MB)
// ---------------------------------------------------------------------------
extern "C" void kernel_launch(void* const* d_in, const int* in_sizes, int n_in,
                              void* d_out, int out_size, void* d_ws,
                              size_t ws_size, hipStream_t stream) {
    const float* query  = (const float*)d_in[0];
    const float* mem    = (const float*)d_in[1];
    const float* scaleb = (const float*)d_in[2];
    float* out = (float*)d_out;

    float* q2 = (float*)d_ws;
    float* m2 = q2 + N_Q;
    float* m2b = m2 + N_M;
    __hip_bfloat16* qb = (__hip_bfloat16*)(m2b + N_M);
    __hip_bfloat16* mb = qb + (size_t)N_Q * DIM;
    unsigned* candK = (unsigned*)(mb + (size_t)N_M * DIM);
    int* candI2 = (int*)(candK + (size_t)N_Q * SPLITS * TSEL);

    prep_kernel<<<(N_Q + N_M) / 4, 256, 0, stream>>>(query, mem, q2, m2, m2b,
                                                     qb, mb);
    dim3 gridB(N_Q / BROWS, SPLITS);
    knn_tops_kernel<<<gridB, 256, 0, stream>>>(qb, mb, m2b, candK);
    merge_kernel<<<N_Q / 256, 256, 0, stream>>>(candK, candI2);
    finalize_kernel<<<N_Q / 4, 256, 0, stream>>>(query, mem, q2, m2, candI2,
                                                 scaleb, out);
}